// Round 13
// baseline (160.602 us; speedup 1.0000x reference)
//
#include <hip/hip_runtime.h>

// MHAttention B=8 T=2048 C=512 H=512, causal, fp32 in/out.
// cast(fp32->fp16) -> fused QKV GEMM (Q row-major; K,V in MFMA-frag order) -> flash.
// R13 flash: 256 WGs x 16 waves, 64-row q-tiles, KVBLK=512 (16 strips = 16 waves).
// Halves L2 traffic vs R12 (K/V amortized over 64 q-rows) and halves per-CU
// step count (longest WG = 4 steps x 1MB port traffic). Transient-register
// discipline throughout (kf/vf in groups of 4, contained scopes).

using short8 = __attribute__((ext_vector_type(8))) short;
using half8  = __attribute__((ext_vector_type(8))) _Float16;
using f32x4  = __attribute__((ext_vector_type(4))) float;
using f32x16 = __attribute__((ext_vector_type(16))) float;

#define B_    8
#define T_    2048
#define SCALE_ 0.044194173824159216f   // 512^-0.5

// flash LDS: Q [64 rows][1KB] f16 (16B-granule XOR row&31) at 0
#define FL_P    65536    // [64 q][1KB] f16 (granule XOR row&31), single buffer
#define FL_STX  131072   // 2 x [64 q][20 f32] (80B padded rows, step parity)
#define FL_STS  141312   // 2 x [64 q][20 f32]
#define FL_SMEM 151552
// epilogue scratch (post-barrier) reuses Q+P: wave wv at wv*4608 (<=73728)

__device__ __forceinline__ void gload_lds16(const void* g, void* l) {
  __builtin_amdgcn_global_load_lds(
      (const __attribute__((address_space(1))) unsigned int*)g,
      (__attribute__((address_space(3))) unsigned int*)l, 16, 0, 0);
}

__device__ __forceinline__ unsigned short f2h(float f) {  // RNE f32->f16 bits
  _Float16 h = (_Float16)f;
  return *(unsigned short*)&h;
}

// barrier waiting only on LDS ops — global loads (vmcnt) stay in flight
__device__ __forceinline__ void barrier_lgkm() {
  asm volatile("s_waitcnt lgkmcnt(0)" ::: "memory");
  __builtin_amdgcn_s_barrier();
  asm volatile("" ::: "memory");
}

// ---------------------------------------------------------------- cast kernel
__global__ __launch_bounds__(256) void cast_kernel(
    const float* __restrict__ x, const float* __restrict__ wq,
    const float* __restrict__ wk, const float* __restrict__ wv,
    unsigned short* __restrict__ xb, unsigned short* __restrict__ wcat) {
  size_t i4 = (size_t)blockIdx.x * 256 + threadIdx.x;   // one float4 per thread
  const size_t NX4 = (size_t)(B_ * T_ * 512) / 4;       // 2097152
  const float* src; unsigned short* dst; size_t off4;
  if (i4 < NX4) { src = x; dst = xb; off4 = i4; }
  else {
    size_t w4 = i4 - NX4;                 // < 196608
    size_t mat = w4 >> 16;                // 65536 float4 per 512x512 matrix
    off4 = w4 & 65535;
    src = (mat == 0) ? wq : (mat == 1) ? wk : wv;
    dst = wcat + (mat << 18);
  }
  float4 v = ((const float4*)src)[off4];
  unsigned long long pk = (unsigned long long)f2h(v.x)
                        | ((unsigned long long)f2h(v.y) << 16)
                        | ((unsigned long long)f2h(v.z) << 32)
                        | ((unsigned long long)f2h(v.w) << 48);
  *(unsigned long long*)(dst + off4 * 4) = pk;
}

// ---------------------------------------------------------------- QKV GEMM
// (unchanged — verified; K/V frag layouts identical)
__device__ __forceinline__ void gemm_stage(
    const unsigned short* __restrict__ xb, const unsigned short* __restrict__ wcat,
    char* smem, int buf, int mbase, int nbase, int kt, int wv, int lane, int srcg) {
  char* base = smem + buf * 32768;
  const int kbase = kt * 64;
  if (wv < 2) {
    #pragma unroll
    for (int i = 0; i < 8; ++i) {
      const int blk = wv * 8 + i;
      const int row = blk * 8 + (lane >> 3);
      gload_lds16(xb + (size_t)(mbase + row) * 512 + kbase + srcg, base + blk * 1024);
    }
  } else {
    #pragma unroll
    for (int i = 0; i < 8; ++i) {
      const int blk = (wv - 2) * 8 + i;
      const int row = blk * 8 + (lane >> 3);
      gload_lds16(wcat + (size_t)(nbase + row) * 512 + kbase + srcg, base + 16384 + blk * 1024);
    }
  }
}

__global__ __launch_bounds__(256, 2) void gemm_qkv(
    const unsigned short* __restrict__ xb, const unsigned short* __restrict__ wcat,
    unsigned short* __restrict__ Qb, unsigned short* __restrict__ Kf,
    unsigned short* __restrict__ Vtb) {
  __shared__ char smem[65536];
  const int tid = threadIdx.x, lane = tid & 63, wv = tid >> 6;
  const int wr = wv >> 1, wc = wv & 1;
  const int l15 = lane & 15, l4 = lane >> 4;
  const int mbase = blockIdx.x * 128;
  const int nbase = blockIdx.y * 128;
  const int srcg = (((lane & 7) ^ ((lane >> 3) & 7))) * 8;

  f32x4 acc[4][4];
  #pragma unroll
  for (int i = 0; i < 4; ++i)
    #pragma unroll
    for (int j = 0; j < 4; ++j) acc[i][j] = (f32x4){0.f, 0.f, 0.f, 0.f};

  gemm_stage(xb, wcat, smem, 0, mbase, nbase, 0, wv, lane, srcg);
  for (int kt = 0; kt < 8; ++kt) {
    __syncthreads();
    if (kt < 7) gemm_stage(xb, wcat, smem, (kt + 1) & 1, mbase, nbase, kt + 1, wv, lane, srcg);
    const char* base = smem + (kt & 1) * 32768;
    #pragma unroll
    for (int ks = 0; ks < 2; ++ks) {
      half8 a[4], b8[4];
      #pragma unroll
      for (int rt = 0; rt < 4; ++rt) {
        const int row = wr * 64 + rt * 16 + l15;
        const int G = (ks * 4 + l4) ^ (row & 7);
        a[rt] = *(const half8*)(base + row * 128 + G * 16);
      }
      #pragma unroll
      for (int ct = 0; ct < 4; ++ct) {
        const int row = wc * 64 + ct * 16 + l15;
        const int G = (ks * 4 + l4) ^ (row & 7);
        b8[ct] = *(const half8*)(base + 16384 + row * 128 + G * 16);
      }
      #pragma unroll
      for (int rt = 0; rt < 4; ++rt)
        #pragma unroll
        for (int ct = 0; ct < 4; ++ct)
          acc[rt][ct] = __builtin_amdgcn_mfma_f32_16x16x32_f16(a[rt], b8[ct], acc[rt][ct], 0, 0, 0);
    }
  }

  const int mat = nbase >> 9;          // 0=Q, 1=K, 2=V
  const int nloc = nbase & 511;
  if (mat == 0) {
    #pragma unroll
    for (int rt = 0; rt < 4; ++rt)
      #pragma unroll
      for (int ct = 0; ct < 4; ++ct) {
        const int m0 = mbase + wr * 64 + rt * 16 + l4 * 4;
        const int n = nloc + wc * 64 + ct * 16 + l15;
        #pragma unroll
        for (int j = 0; j < 4; ++j)
          Qb[(size_t)(m0 + j) * 512 + n] = f2h(acc[rt][ct][j]);
      }
  } else if (mat == 1) {
    // K in flash A-frag order
    #pragma unroll
    for (int rt = 0; rt < 4; ++rt)
      #pragma unroll
      for (int ct = 0; ct < 4; ++ct) {
        const int m0 = mbase + wr * 64 + rt * 16 + l4 * 4;
        const int d = nloc + wc * 64 + ct * 16 + l15;
        const int s = d >> 4, hh = (d >> 3) & 1, e = d & 7;
        #pragma unroll
        for (int j = 0; j < 4; ++j) {
          const int t = m0 + j;
          const int bb = t >> 11, tt = t & 2047;
          const size_t blk =
              ((((size_t)bb * 64 + (tt >> 5)) * 32 + s) * 32 + (tt & 31)) * 2 + hh;
          Kf[blk * 8 + e] = f2h(acc[rt][ct][j]);
        }
      }
  } else {
    // V in flash frag order; j..j+3 stay within one 16B block
    #pragma unroll
    for (int rt = 0; rt < 4; ++rt)
      #pragma unroll
      for (int ct = 0; ct < 4; ++ct) {
        const int m0 = mbase + wr * 64 + rt * 16 + l4 * 4;
        const int d = nloc + wc * 64 + ct * 16 + l15;
        const int bb = m0 >> 11, t = m0 & 2047;
        const int kvt = t >> 7, u = (t >> 3) & 15, jj = t & 7;
        unsigned long long pk = (unsigned long long)f2h(acc[rt][ct][0])
                              | ((unsigned long long)f2h(acc[rt][ct][1]) << 16)
                              | ((unsigned long long)f2h(acc[rt][ct][2]) << 32)
                              | ((unsigned long long)f2h(acc[rt][ct][3]) << 48);
        *(unsigned long long*)(Vtb + ((((size_t)bb * 16 + kvt) * 16 + u) * 512 + d) * 8 + jj) = pk;
      }
  }
}

// ---------------------------------------------------------------- flash attention
// 256 WGs x 16 waves; b = blk&7 (XCD), qt = 31-(blk>>3) (64 q-rows, long first).
// nkv = (qt+8)>>3 steps of KVBLK=512 (max 4).
// QK: wave ks=wv (strip 32 kv): TWO chains = both q-halves off one kf read.
// PV: wave owns d strip [wv*32..+32): O^T[q2] += mfma32(V_frag, P_lds).
// Per step (parity p): [if strip live: kf groups-of-4 + QK both halves] ->
//   mask/max -> stx[p] -> lgkmB -> softmax (halves sequential) -> P+sts[p] ->
//   lgkmC -> rescale -> PV (8 groups of 4 chunks, masked groups skipped).
__global__ __launch_bounds__(1024, 1) void flash_kernel(
    const unsigned short* __restrict__ Qb, const unsigned short* __restrict__ Kf,
    const unsigned short* __restrict__ Vtb, float* __restrict__ out) {
  extern __shared__ char smem[];

  const int tid = threadIdx.x, lane = tid & 63, wv = tid >> 6;   // 16 waves
  const int l31 = lane & 31, h = lane >> 5;
  const int ks = wv;                               // kv strip 0..15 in 512-block
  const int b = blockIdx.x & 7;                    // batch == XCD
  const int qt = 31 - (blockIdx.x >> 3);           // 64-row tile, long first
  const size_t bT = (size_t)b * T_;
  const int nkv = (qt + 8) >> 3;
  const int qmax = qt * 64 + 63;

  // ---- stage Q [64][512] once: LDS[r] granule g = Q[r][g ^ (r&31)] ----
  {
    const unsigned short* src = Qb + (bT + (size_t)qt * 64) * 512;
    #pragma unroll
    for (int i = 0; i < 4; ++i) {
      const int r = wv * 4 + i;
      gload_lds16(src + (size_t)r * 512 + ((lane ^ (r & 31)) * 8), smem + r * 1024);
    }
  }
  asm volatile("s_waitcnt vmcnt(0)" ::: "memory");
  __builtin_amdgcn_s_barrier();

  f32x16 o[2];                                     // o[q2]: O^T [32 d][32 q]
  #pragma unroll
  for (int q2 = 0; q2 < 2; ++q2)
    #pragma unroll
    for (int r = 0; r < 16; ++r) o[q2][r] = 0.f;
  float lreg[2] = {0.f, 0.f};
  float mqpv[2] = {-1e30f, -1e30f};
  float mqk[2] = {-1e30f, -1e30f};

  for (int kv = 0; kv < nkv; ++kv) {
    const int kv0 = kv * 512;
    const int p = kv & 1;
    char* Pp = smem + FL_P;
    float* stxp = (float*)(smem + FL_STX + p * 5120);
    float* stsp = (float*)(smem + FL_STS + p * 5120);

    // ---- QK^T swapped, both q-halves off one kf read (contained scope) ----
    f32x16 acc0, acc1;
    #pragma unroll
    for (int r = 0; r < 16; ++r) { acc0[r] = 0.f; acc1[r] = 0.f; }
    if (kv0 + ks * 32 <= qmax) {                   // wave-uniform strip skip
      const unsigned short* kp =
          Kf + (((size_t)b * 64 + (kv * 16 + ks)) << 14) + l31 * 16 + h * 8;
      const char* qb0 = smem + l31 * 1024;
      const char* qb1 = smem + (32 + l31) * 1024;
      #pragma unroll
      for (int sg = 0; sg < 8; ++sg) {             // groups of 4: kf transient
        half8 kf4[4];
        #pragma unroll
        for (int i = 0; i < 4; ++i)
          kf4[i] = *(const half8*)(kp + (sg * 4 + i) * 512);
        #pragma unroll
        for (int i = 0; i < 4; ++i) {
          const int go = (((sg * 4 + i) * 2 + h) ^ l31) << 4;
          acc0 = __builtin_amdgcn_mfma_f32_32x32x16_f16(kf4[i], *(const half8*)(qb0 + go), acc0, 0, 0, 0);
          acc1 = __builtin_amdgcn_mfma_f32_32x32x16_f16(kf4[i], *(const half8*)(qb1 + go), acc1, 0, 0, 0);
        }
      }
    }

    // ---- scale + causal mask + in-lane strip max (both halves) ----
    float v0[16], v1[16], tm0 = -1e30f, tm1 = -1e30f;
    #pragma unroll
    for (int r = 0; r < 16; ++r) {
      const int kvg = kv0 + ks * 32 + (r & 3) + 8 * (r >> 2) + 4 * h;
      v0[r] = (kvg <= qt * 64 + l31) ? acc0[r] * SCALE_ : -1e30f;
      v1[r] = (kvg <= qt * 64 + 32 + l31) ? acc1[r] * SCALE_ : -1e30f;
      tm0 = fmaxf(tm0, v0[r]);
      tm1 = fmaxf(tm1, v1[r]);
    }
    tm0 = fmaxf(tm0, __shfl_xor(tm0, 32, 64));
    tm1 = fmaxf(tm1, __shfl_xor(tm1, 32, 64));
    if (h == 0) { stxp[l31 * 20 + ks] = tm0; stxp[(32 + l31) * 20 + ks] = tm1; }
    barrier_lgkm();                                // B: strip maxes visible

    // ---- softmax (halves sequential; per-lane scalar state) ----
    #pragma unroll
    for (int hf = 0; hf < 2; ++hf) {
      const int r0 = hf * 32 + l31;
      const float* sx = stxp + r0 * 20;
      float mn = mqk[hf];
      #pragma unroll
      for (int i = 0; i < 4; ++i) {
        const f32x4 x = *(const f32x4*)(sx + i * 4);
        mn = fmaxf(mn, fmaxf(fmaxf(x[0], x[1]), fmaxf(x[2], x[3])));
      }
      mqk[hf] = mn;
      const float* vv = hf ? v1 : v0;
      float ps = 0.f;
      #pragma unroll
      for (int c = 0; c < 4; ++c) {                // P -> LDS, b64 packed
        unsigned long long pk = 0;
        #pragma unroll
        for (int j = 0; j < 4; ++j) {
          const unsigned short hj = f2h(__expf(vv[4 * c + j] - mn));
          ps += (float)*(const _Float16*)&hj;      // sum the rounded values
          pk |= (unsigned long long)hj << (16 * j);
        }
        *(unsigned long long*)(Pp + r0 * 1024 +
                               ((((ks * 4 + c) ^ (r0 & 31))) << 4) + h * 8) = pk;
      }
      ps += __shfl_xor(ps, 32, 64);
      if (h == 0) stsp[r0 * 20 + ks] = ps;
    }
    barrier_lgkm();                                // C: P + stats visible

    // ---- per-lane alpha/l update, rescale O ----
    #pragma unroll
    for (int q2 = 0; q2 < 2; ++q2) {
      const int r0 = q2 * 32 + l31;
      const float* sx = stxp + r0 * 20;
      float mn2 = mqpv[q2];
      #pragma unroll
      for (int i = 0; i < 4; ++i) {
        const f32x4 x = *(const f32x4*)(sx + i * 4);
        mn2 = fmaxf(mn2, fmaxf(fmaxf(x[0], x[1]), fmaxf(x[2], x[3])));
      }
      const float a = __expf(mqpv[q2] - mn2);
      mqpv[q2] = mn2;
      const float* ss = stsp + r0 * 20;
      float sum = 0.f;
      #pragma unroll
      for (int i = 0; i < 4; ++i) {
        const f32x4 x = *(const f32x4*)(ss + i * 4);
        sum += (x[0] + x[1]) + (x[2] + x[3]);
      }
      lreg[q2] = a * lreg[q2] + sum;
      #pragma unroll
      for (int r = 0; r < 16; ++r) o[q2][r] *= a;
    }

    // ---- PV: O^T += Vt x P over 512 kv; 8 groups of 4 chunks (vf transient),
    // ---- fully-masked groups skipped (wave-uniform) ----
    const int d = wv * 32 + l31;
    #pragma unroll
    for (int g = 0; g < 8; ++g) {
      if (kv0 + g * 64 <= qmax) {
        half8 vf[4];
        #pragma unroll
        for (int s4 = 0; s4 < 4; ++s4) {
          const int S = g * 4 + s4;
          const size_t vblk = ((size_t)b * 16 + (kv * 4 + (S >> 3))) * 16;
          vf[s4] = *(const half8*)(Vtb + ((vblk + (S & 7) * 2 + h) * 512 + d) * 8);
        }
        #pragma unroll
        for (int s4 = 0; s4 < 4; ++s4) {
          const int S = g * 4 + s4;
          #pragma unroll
          for (int q2 = 0; q2 < 2; ++q2) {
            const half8 pa = *(const half8*)(Pp + (q2 * 32 + l31) * 1024 +
                                             (((S * 2 + h) ^ l31) << 4));
            o[q2] = __builtin_amdgcn_mfma_f32_32x32x16_f16(vf[s4], pa, o[q2], 0, 0, 0);
          }
        }
      }
    }
  }

  barrier_lgkm();                                  // all PV P-reads done (scratch reuse)

  // ---- epilogue: transpose O^T via per-wave scratch, /l, coalesced stores ----
  {
    char* scr = smem + wv * 4608;                  // 32 rows x 144B
    const float linv[2] = {1.0f / lreg[0], 1.0f / lreg[1]};
    #pragma unroll
    for (int q2 = 0; q2 < 2; ++q2) {
      #pragma unroll
      for (int c = 0; c < 4; ++c) {
        f32x4 w4;
        #pragma unroll
        for (int j = 0; j < 4; ++j) w4[j] = o[q2][4 * c + j] * linv[q2];
        *(f32x4*)(scr + l31 * 144 + c * 32 + h * 16) = w4;   // scr[q][d]
      }
      asm volatile("s_waitcnt lgkmcnt(0)" ::: "memory");
      #pragma unroll
      for (int g = 0; g < 4; ++g) {
        const int qr = g * 8 + (lane >> 3);
        const f32x4 r4 = *(const f32x4*)(scr + qr * 144 + (lane & 7) * 16);
        *(f32x4*)(out + (bT + qt * 64 + q2 * 32 + qr) * 512 +
                  wv * 32 + (lane & 7) * 4) = r4;
      }
      asm volatile("s_waitcnt lgkmcnt(0)" ::: "memory");
    }
  }
}

// ---------------------------------------------------------------- launch
extern "C" void kernel_launch(void* const* d_in, const int* in_sizes, int n_in,
                              void* d_out, int out_size, void* d_ws, size_t ws_size,
                              hipStream_t stream) {
  (void)in_sizes; (void)n_in; (void)out_size; (void)ws_size;
  const float* x  = (const float*)d_in[0];
  const float* wq = (const float*)d_in[1];
  const float* wk = (const float*)d_in[2];
  const float* wv = (const float*)d_in[3];
  float* out = (float*)d_out;

  unsigned short* ws   = (unsigned short*)d_ws;
  unsigned short* xb   = ws;                                    // [16384][512]
  unsigned short* wcat = xb + (size_t)16384 * 512;              // [1536][512]
  unsigned short* Qb   = wcat + (size_t)1536 * 512;             // [16384][512] row-major
  unsigned short* Kf   = Qb + (size_t)16384 * 512;              // [8][64][32][32][2][8] frag order
  unsigned short* Vtb  = Kf + (size_t)16384 * 512;              // [8][16][16][512][8] frag order
  // total ws use: 68.7 MB

  cast_kernel<<<8960, 256, 0, stream>>>(x, wq, wk, wv, xb, wcat);
  gemm_qkv<<<dim3(128, 12), 256, 0, stream>>>(xb, wcat, Qb, Kf, Vtb);
  hipFuncSetAttribute(reinterpret_cast<const void*>(flash_kernel),
                      hipFuncAttributeMaxDynamicSharedMemorySize, FL_SMEM);
  flash_kernel<<<256, 1024, FL_SMEM, stream>>>(Qb, Kf, Vtb, out);
}

// Round 14
// 150.917 us; speedup vs baseline: 1.0642x; 1.0642x over previous
//
#include <hip/hip_runtime.h>

// MHAttention B=8 T=2048 C=512 H=512, causal, fp32 in/out.
// cast(fp32->fp16) -> fused QKV GEMM (Q row-major; K,V in MFMA-frag order) -> flash.
// R14 flash = R13 (64-row q-tiles, KVBLK=512, 16 waves) minus its two spill
// sources: (1) v0/v1 arrays eliminated — causal mask+scale applied IN PLACE to
// the QK accumulators; (2) all wave-uniform guards removed (fully unconditional
// control flow, R12-proven form; masked strips produce P=0 harmlessly).
// Peak live VGPRs ~100 < 128 cap.

using short8 = __attribute__((ext_vector_type(8))) short;
using half8  = __attribute__((ext_vector_type(8))) _Float16;
using f32x4  = __attribute__((ext_vector_type(4))) float;
using f32x16 = __attribute__((ext_vector_type(16))) float;

#define B_    8
#define T_    2048
#define SCALE_ 0.044194173824159216f   // 512^-0.5

// flash LDS: Q [64 rows][1KB] f16 (16B-granule XOR row&31) at 0
#define FL_P    65536    // [64 q][1KB] f16 (granule XOR row&31), single buffer
#define FL_STX  131072   // 2 x [64 q][20 f32] (80B padded rows, step parity)
#define FL_STS  141312   // 2 x [64 q][20 f32]
#define FL_SMEM 151552
// epilogue scratch (post-barrier) reuses Q+P: wave wv at wv*4608 (<=73728)

__device__ __forceinline__ void gload_lds16(const void* g, void* l) {
  __builtin_amdgcn_global_load_lds(
      (const __attribute__((address_space(1))) unsigned int*)g,
      (__attribute__((address_space(3))) unsigned int*)l, 16, 0, 0);
}

__device__ __forceinline__ unsigned short f2h(float f) {  // RNE f32->f16 bits
  _Float16 h = (_Float16)f;
  return *(unsigned short*)&h;
}

// barrier waiting only on LDS ops — global loads (vmcnt) stay in flight
__device__ __forceinline__ void barrier_lgkm() {
  asm volatile("s_waitcnt lgkmcnt(0)" ::: "memory");
  __builtin_amdgcn_s_barrier();
  asm volatile("" ::: "memory");
}

// ---------------------------------------------------------------- cast kernel
__global__ __launch_bounds__(256) void cast_kernel(
    const float* __restrict__ x, const float* __restrict__ wq,
    const float* __restrict__ wk, const float* __restrict__ wv,
    unsigned short* __restrict__ xb, unsigned short* __restrict__ wcat) {
  size_t i4 = (size_t)blockIdx.x * 256 + threadIdx.x;   // one float4 per thread
  const size_t NX4 = (size_t)(B_ * T_ * 512) / 4;       // 2097152
  const float* src; unsigned short* dst; size_t off4;
  if (i4 < NX4) { src = x; dst = xb; off4 = i4; }
  else {
    size_t w4 = i4 - NX4;                 // < 196608
    size_t mat = w4 >> 16;                // 65536 float4 per 512x512 matrix
    off4 = w4 & 65535;
    src = (mat == 0) ? wq : (mat == 1) ? wk : wv;
    dst = wcat + (mat << 18);
  }
  float4 v = ((const float4*)src)[off4];
  unsigned long long pk = (unsigned long long)f2h(v.x)
                        | ((unsigned long long)f2h(v.y) << 16)
                        | ((unsigned long long)f2h(v.z) << 32)
                        | ((unsigned long long)f2h(v.w) << 48);
  *(unsigned long long*)(dst + off4 * 4) = pk;
}

// ---------------------------------------------------------------- QKV GEMM
// (unchanged — verified; K/V frag layouts identical)
__device__ __forceinline__ void gemm_stage(
    const unsigned short* __restrict__ xb, const unsigned short* __restrict__ wcat,
    char* smem, int buf, int mbase, int nbase, int kt, int wv, int lane, int srcg) {
  char* base = smem + buf * 32768;
  const int kbase = kt * 64;
  if (wv < 2) {
    #pragma unroll
    for (int i = 0; i < 8; ++i) {
      const int blk = wv * 8 + i;
      const int row = blk * 8 + (lane >> 3);
      gload_lds16(xb + (size_t)(mbase + row) * 512 + kbase + srcg, base + blk * 1024);
    }
  } else {
    #pragma unroll
    for (int i = 0; i < 8; ++i) {
      const int blk = (wv - 2) * 8 + i;
      const int row = blk * 8 + (lane >> 3);
      gload_lds16(wcat + (size_t)(nbase + row) * 512 + kbase + srcg, base + 16384 + blk * 1024);
    }
  }
}

__global__ __launch_bounds__(256, 2) void gemm_qkv(
    const unsigned short* __restrict__ xb, const unsigned short* __restrict__ wcat,
    unsigned short* __restrict__ Qb, unsigned short* __restrict__ Kf,
    unsigned short* __restrict__ Vtb) {
  __shared__ char smem[65536];
  const int tid = threadIdx.x, lane = tid & 63, wv = tid >> 6;
  const int wr = wv >> 1, wc = wv & 1;
  const int l15 = lane & 15, l4 = lane >> 4;
  const int mbase = blockIdx.x * 128;
  const int nbase = blockIdx.y * 128;
  const int srcg = (((lane & 7) ^ ((lane >> 3) & 7))) * 8;

  f32x4 acc[4][4];
  #pragma unroll
  for (int i = 0; i < 4; ++i)
    #pragma unroll
    for (int j = 0; j < 4; ++j) acc[i][j] = (f32x4){0.f, 0.f, 0.f, 0.f};

  gemm_stage(xb, wcat, smem, 0, mbase, nbase, 0, wv, lane, srcg);
  for (int kt = 0; kt < 8; ++kt) {
    __syncthreads();
    if (kt < 7) gemm_stage(xb, wcat, smem, (kt + 1) & 1, mbase, nbase, kt + 1, wv, lane, srcg);
    const char* base = smem + (kt & 1) * 32768;
    #pragma unroll
    for (int ks = 0; ks < 2; ++ks) {
      half8 a[4], b8[4];
      #pragma unroll
      for (int rt = 0; rt < 4; ++rt) {
        const int row = wr * 64 + rt * 16 + l15;
        const int G = (ks * 4 + l4) ^ (row & 7);
        a[rt] = *(const half8*)(base + row * 128 + G * 16);
      }
      #pragma unroll
      for (int ct = 0; ct < 4; ++ct) {
        const int row = wc * 64 + ct * 16 + l15;
        const int G = (ks * 4 + l4) ^ (row & 7);
        b8[ct] = *(const half8*)(base + 16384 + row * 128 + G * 16);
      }
      #pragma unroll
      for (int rt = 0; rt < 4; ++rt)
        #pragma unroll
        for (int ct = 0; ct < 4; ++ct)
          acc[rt][ct] = __builtin_amdgcn_mfma_f32_16x16x32_f16(a[rt], b8[ct], acc[rt][ct], 0, 0, 0);
    }
  }

  const int mat = nbase >> 9;          // 0=Q, 1=K, 2=V
  const int nloc = nbase & 511;
  if (mat == 0) {
    #pragma unroll
    for (int rt = 0; rt < 4; ++rt)
      #pragma unroll
      for (int ct = 0; ct < 4; ++ct) {
        const int m0 = mbase + wr * 64 + rt * 16 + l4 * 4;
        const int n = nloc + wc * 64 + ct * 16 + l15;
        #pragma unroll
        for (int j = 0; j < 4; ++j)
          Qb[(size_t)(m0 + j) * 512 + n] = f2h(acc[rt][ct][j]);
      }
  } else if (mat == 1) {
    // K in flash A-frag order
    #pragma unroll
    for (int rt = 0; rt < 4; ++rt)
      #pragma unroll
      for (int ct = 0; ct < 4; ++ct) {
        const int m0 = mbase + wr * 64 + rt * 16 + l4 * 4;
        const int d = nloc + wc * 64 + ct * 16 + l15;
        const int s = d >> 4, hh = (d >> 3) & 1, e = d & 7;
        #pragma unroll
        for (int j = 0; j < 4; ++j) {
          const int t = m0 + j;
          const int bb = t >> 11, tt = t & 2047;
          const size_t blk =
              ((((size_t)bb * 64 + (tt >> 5)) * 32 + s) * 32 + (tt & 31)) * 2 + hh;
          Kf[blk * 8 + e] = f2h(acc[rt][ct][j]);
        }
      }
  } else {
    // V in flash frag order; j..j+3 stay within one 16B block
    #pragma unroll
    for (int rt = 0; rt < 4; ++rt)
      #pragma unroll
      for (int ct = 0; ct < 4; ++ct) {
        const int m0 = mbase + wr * 64 + rt * 16 + l4 * 4;
        const int d = nloc + wc * 64 + ct * 16 + l15;
        const int bb = m0 >> 11, t = m0 & 2047;
        const int kvt = t >> 7, u = (t >> 3) & 15, jj = t & 7;
        unsigned long long pk = (unsigned long long)f2h(acc[rt][ct][0])
                              | ((unsigned long long)f2h(acc[rt][ct][1]) << 16)
                              | ((unsigned long long)f2h(acc[rt][ct][2]) << 32)
                              | ((unsigned long long)f2h(acc[rt][ct][3]) << 48);
        *(unsigned long long*)(Vtb + ((((size_t)bb * 16 + kvt) * 16 + u) * 512 + d) * 8 + jj) = pk;
      }
  }
}

// ---------------------------------------------------------------- flash attention
// 256 WGs x 16 waves; b = blk&7 (XCD), qt = 31-(blk>>3) (64 q-rows, long first).
// nkv = (qt+8)>>3 steps of KVBLK=512 (max 4). Fully unconditional control flow.
// QK: wave ks=wv (strip 32 kv): TWO chains = both q-halves off one kf read;
//     causal mask+scale IN PLACE into the accumulators (no v[] arrays).
// PV: wave owns d strip [wv*32..+32): O^T[q2] += mfma32(V_frag, P_lds).
__global__ __launch_bounds__(1024, 1) void flash_kernel(
    const unsigned short* __restrict__ Qb, const unsigned short* __restrict__ Kf,
    const unsigned short* __restrict__ Vtb, float* __restrict__ out) {
  extern __shared__ char smem[];

  const int tid = threadIdx.x, lane = tid & 63, wv = tid >> 6;   // 16 waves
  const int l31 = lane & 31, h = lane >> 5;
  const int ks = wv;                               // kv strip 0..15 in 512-block
  const int b = blockIdx.x & 7;                    // batch == XCD
  const int qt = 31 - (blockIdx.x >> 3);           // 64-row tile, long first
  const size_t bT = (size_t)b * T_;
  const int nkv = (qt + 8) >> 3;

  // ---- stage Q [64][512] once: LDS[r] granule g = Q[r][g ^ (r&31)] ----
  {
    const unsigned short* src = Qb + (bT + (size_t)qt * 64) * 512;
    #pragma unroll
    for (int i = 0; i < 4; ++i) {
      const int r = wv * 4 + i;
      gload_lds16(src + (size_t)r * 512 + ((lane ^ (r & 31)) * 8), smem + r * 1024);
    }
  }
  asm volatile("s_waitcnt vmcnt(0)" ::: "memory");
  __builtin_amdgcn_s_barrier();

  f32x16 o[2];                                     // o[q2]: O^T [32 d][32 q]
  #pragma unroll
  for (int q2 = 0; q2 < 2; ++q2)
    #pragma unroll
    for (int r = 0; r < 16; ++r) o[q2][r] = 0.f;
  float lreg[2] = {0.f, 0.f};
  float mqpv[2] = {-1e30f, -1e30f};
  float mqk[2] = {-1e30f, -1e30f};

  for (int kv = 0; kv < nkv; ++kv) {
    const int kv0 = kv * 512;
    const int p = kv & 1;
    char* Pp = smem + FL_P;
    float* stxp = (float*)(smem + FL_STX + p * 5120);
    float* stsp = (float*)(smem + FL_STS + p * 5120);

    // ---- QK^T swapped, both q-halves off one kf read (unconditional) ----
    f32x16 acc0, acc1;
    #pragma unroll
    for (int r = 0; r < 16; ++r) { acc0[r] = 0.f; acc1[r] = 0.f; }
    {
      const unsigned short* kp =
          Kf + (((size_t)b * 64 + (kv * 16 + ks)) << 14) + l31 * 16 + h * 8;
      const char* qb0 = smem + l31 * 1024;
      const char* qb1 = smem + (32 + l31) * 1024;
      #pragma unroll
      for (int sg = 0; sg < 8; ++sg) {             // groups of 4: kf transient
        half8 kf4[4];
        #pragma unroll
        for (int i = 0; i < 4; ++i)
          kf4[i] = *(const half8*)(kp + (sg * 4 + i) * 512);
        #pragma unroll
        for (int i = 0; i < 4; ++i) {
          const int go = (((sg * 4 + i) * 2 + h) ^ l31) << 4;
          acc0 = __builtin_amdgcn_mfma_f32_32x32x16_f16(kf4[i], *(const half8*)(qb0 + go), acc0, 0, 0, 0);
          acc1 = __builtin_amdgcn_mfma_f32_32x32x16_f16(kf4[i], *(const half8*)(qb1 + go), acc1, 0, 0, 0);
        }
      }
    }

    // ---- scale + causal mask IN PLACE + in-lane strip max ----
    float tm0 = -1e30f, tm1 = -1e30f;
    {
      const int qg0 = qt * 64 + l31;
      const int qg1 = qg0 + 32;
      #pragma unroll
      for (int r = 0; r < 16; ++r) {
        const int kvg = kv0 + ks * 32 + (r & 3) + 8 * (r >> 2) + 4 * h;
        acc0[r] = (kvg <= qg0) ? acc0[r] * SCALE_ : -1e30f;
        acc1[r] = (kvg <= qg1) ? acc1[r] * SCALE_ : -1e30f;
        tm0 = fmaxf(tm0, acc0[r]);
        tm1 = fmaxf(tm1, acc1[r]);
      }
    }
    tm0 = fmaxf(tm0, __shfl_xor(tm0, 32, 64));
    tm1 = fmaxf(tm1, __shfl_xor(tm1, 32, 64));
    if (h == 0) { stxp[l31 * 20 + ks] = tm0; stxp[(32 + l31) * 20 + ks] = tm1; }
    barrier_lgkm();                                // B: strip maxes visible

    // ---- softmax (halves sequential; per-lane scalar state; acc read direct) ----
    #pragma unroll
    for (int hf = 0; hf < 2; ++hf) {
      const int r0 = hf * 32 + l31;
      const float* sx = stxp + r0 * 20;
      float mn = mqk[hf];
      #pragma unroll
      for (int i = 0; i < 4; ++i) {
        const f32x4 x = *(const f32x4*)(sx + i * 4);
        mn = fmaxf(mn, fmaxf(fmaxf(x[0], x[1]), fmaxf(x[2], x[3])));
      }
      mqk[hf] = mn;
      const f32x16& vv = hf ? acc1 : acc0;
      float ps = 0.f;
      #pragma unroll
      for (int c = 0; c < 4; ++c) {                // P -> LDS, b64 packed
        unsigned long long pk = 0;
        #pragma unroll
        for (int j = 0; j < 4; ++j) {
          const unsigned short hj = f2h(__expf(vv[4 * c + j] - mn));
          ps += (float)*(const _Float16*)&hj;      // sum the rounded values
          pk |= (unsigned long long)hj << (16 * j);
        }
        *(unsigned long long*)(Pp + r0 * 1024 +
                               ((((ks * 4 + c) ^ (r0 & 31))) << 4) + h * 8) = pk;
      }
      ps += __shfl_xor(ps, 32, 64);
      if (h == 0) stsp[r0 * 20 + ks] = ps;
    }
    barrier_lgkm();                                // C: P + stats visible

    // ---- per-lane alpha/l update, rescale O ----
    #pragma unroll
    for (int q2 = 0; q2 < 2; ++q2) {
      const int r0 = q2 * 32 + l31;
      const float* sx = stxp + r0 * 20;
      float mn2 = mqpv[q2];
      #pragma unroll
      for (int i = 0; i < 4; ++i) {
        const f32x4 x = *(const f32x4*)(sx + i * 4);
        mn2 = fmaxf(mn2, fmaxf(fmaxf(x[0], x[1]), fmaxf(x[2], x[3])));
      }
      const float a = __expf(mqpv[q2] - mn2);
      mqpv[q2] = mn2;
      const float* ss = stsp + r0 * 20;
      float sum = 0.f;
      #pragma unroll
      for (int i = 0; i < 4; ++i) {
        const f32x4 x = *(const f32x4*)(ss + i * 4);
        sum += (x[0] + x[1]) + (x[2] + x[3]);
      }
      lreg[q2] = a * lreg[q2] + sum;
      #pragma unroll
      for (int r = 0; r < 16; ++r) o[q2][r] *= a;
    }

    // ---- PV: O^T += Vt x P over 512 kv; 8 groups of 4 chunks (vf transient),
    // ---- unconditional (masked chunks have P=0) ----
    const int d = wv * 32 + l31;
    #pragma unroll
    for (int g = 0; g < 8; ++g) {
      half8 vf[4];
      #pragma unroll
      for (int s4 = 0; s4 < 4; ++s4) {
        const int S = g * 4 + s4;
        const size_t vblk = ((size_t)b * 16 + (kv * 4 + (S >> 3))) * 16;
        vf[s4] = *(const half8*)(Vtb + ((vblk + (S & 7) * 2 + h) * 512 + d) * 8);
      }
      #pragma unroll
      for (int s4 = 0; s4 < 4; ++s4) {
        const int S = g * 4 + s4;
        #pragma unroll
        for (int q2 = 0; q2 < 2; ++q2) {
          const half8 pa = *(const half8*)(Pp + (q2 * 32 + l31) * 1024 +
                                           (((S * 2 + h) ^ l31) << 4));
          o[q2] = __builtin_amdgcn_mfma_f32_32x32x16_f16(vf[s4], pa, o[q2], 0, 0, 0);
        }
      }
    }
  }

  barrier_lgkm();                                  // all PV P-reads done (scratch reuse)

  // ---- epilogue: transpose O^T via per-wave scratch, /l, coalesced stores ----
  {
    char* scr = smem + wv * 4608;                  // 32 rows x 144B
    const float linv[2] = {1.0f / lreg[0], 1.0f / lreg[1]};
    #pragma unroll
    for (int q2 = 0; q2 < 2; ++q2) {
      #pragma unroll
      for (int c = 0; c < 4; ++c) {
        f32x4 w4;
        #pragma unroll
        for (int j = 0; j < 4; ++j) w4[j] = o[q2][4 * c + j] * linv[q2];
        *(f32x4*)(scr + l31 * 144 + c * 32 + h * 16) = w4;   // scr[q][d]
      }
      asm volatile("s_waitcnt lgkmcnt(0)" ::: "memory");
      #pragma unroll
      for (int g = 0; g < 4; ++g) {
        const int qr = g * 8 + (lane >> 3);
        const f32x4 r4 = *(const f32x4*)(scr + qr * 144 + (lane & 7) * 16);
        *(f32x4*)(out + (bT + qt * 64 + q2 * 32 + qr) * 512 +
                  wv * 32 + (lane & 7) * 4) = r4;
      }
      asm volatile("s_waitcnt lgkmcnt(0)" ::: "memory");
    }
  }
}

// ---------------------------------------------------------------- launch
extern "C" void kernel_launch(void* const* d_in, const int* in_sizes, int n_in,
                              void* d_out, int out_size, void* d_ws, size_t ws_size,
                              hipStream_t stream) {
  (void)in_sizes; (void)n_in; (void)out_size; (void)ws_size;
  const float* x  = (const float*)d_in[0];
  const float* wq = (const float*)d_in[1];
  const float* wk = (const float*)d_in[2];
  const float* wv = (const float*)d_in[3];
  float* out = (float*)d_out;

  unsigned short* ws   = (unsigned short*)d_ws;
  unsigned short* xb   = ws;                                    // [16384][512]
  unsigned short* wcat = xb + (size_t)16384 * 512;              // [1536][512]
  unsigned short* Qb   = wcat + (size_t)1536 * 512;             // [16384][512] row-major
  unsigned short* Kf   = Qb + (size_t)16384 * 512;              // [8][64][32][32][2][8] frag order
  unsigned short* Vtb  = Kf + (size_t)16384 * 512;              // [8][16][16][512][8] frag order
  // total ws use: 68.7 MB

  cast_kernel<<<8960, 256, 0, stream>>>(x, wq, wk, wv, xb, wcat);
  gemm_qkv<<<dim3(128, 12), 256, 0, stream>>>(xb, wcat, Qb, Kf, Vtb);
  hipFuncSetAttribute(reinterpret_cast<const void*>(flash_kernel),
                      hipFuncAttributeMaxDynamicSharedMemorySize, FL_SMEM);
  flash_kernel<<<256, 1024, FL_SMEM, stream>>>(Qb, Kf, Vtb, out);
}

// Round 15
// 150.787 us; speedup vs baseline: 1.0651x; 1.0009x over previous
//
#include <hip/hip_runtime.h>

// MHAttention B=8 T=2048 C=512 H=512, causal, fp32 in/out.
// cast(fp32->fp16) -> fused QKV GEMM (Q row-major; K,V in MFMA-frag order) -> flash.
// R15 = R14 with ONE change: __launch_bounds__(1024, 4) — the 2nd arg is MIN
// WAVES PER EU; (1024,1) let hipcc's default heuristic target 8 waves/EU and
// allocate only 64 VGPRs (spills). 4 waves/EU = our actual 1-WG/CU occupancy
// -> 128-VGPR budget for the ~100-reg live set.

using short8 = __attribute__((ext_vector_type(8))) short;
using half8  = __attribute__((ext_vector_type(8))) _Float16;
using f32x4  = __attribute__((ext_vector_type(4))) float;
using f32x16 = __attribute__((ext_vector_type(16))) float;

#define B_    8
#define T_    2048
#define SCALE_ 0.044194173824159216f   // 512^-0.5

// flash LDS: Q [64 rows][1KB] f16 (16B-granule XOR row&31) at 0
#define FL_P    65536    // [64 q][1KB] f16 (granule XOR row&31), single buffer
#define FL_STX  131072   // 2 x [64 q][20 f32] (80B padded rows, step parity)
#define FL_STS  141312   // 2 x [64 q][20 f32]
#define FL_SMEM 151552
// epilogue scratch (post-barrier) reuses Q+P: wave wv at wv*4608 (<=73728)

__device__ __forceinline__ void gload_lds16(const void* g, void* l) {
  __builtin_amdgcn_global_load_lds(
      (const __attribute__((address_space(1))) unsigned int*)g,
      (__attribute__((address_space(3))) unsigned int*)l, 16, 0, 0);
}

__device__ __forceinline__ unsigned short f2h(float f) {  // RNE f32->f16 bits
  _Float16 h = (_Float16)f;
  return *(unsigned short*)&h;
}

// barrier waiting only on LDS ops — global loads (vmcnt) stay in flight
__device__ __forceinline__ void barrier_lgkm() {
  asm volatile("s_waitcnt lgkmcnt(0)" ::: "memory");
  __builtin_amdgcn_s_barrier();
  asm volatile("" ::: "memory");
}

// ---------------------------------------------------------------- cast kernel
__global__ __launch_bounds__(256) void cast_kernel(
    const float* __restrict__ x, const float* __restrict__ wq,
    const float* __restrict__ wk, const float* __restrict__ wv,
    unsigned short* __restrict__ xb, unsigned short* __restrict__ wcat) {
  size_t i4 = (size_t)blockIdx.x * 256 + threadIdx.x;   // one float4 per thread
  const size_t NX4 = (size_t)(B_ * T_ * 512) / 4;       // 2097152
  const float* src; unsigned short* dst; size_t off4;
  if (i4 < NX4) { src = x; dst = xb; off4 = i4; }
  else {
    size_t w4 = i4 - NX4;                 // < 196608
    size_t mat = w4 >> 16;                // 65536 float4 per 512x512 matrix
    off4 = w4 & 65535;
    src = (mat == 0) ? wq : (mat == 1) ? wk : wv;
    dst = wcat + (mat << 18);
  }
  float4 v = ((const float4*)src)[off4];
  unsigned long long pk = (unsigned long long)f2h(v.x)
                        | ((unsigned long long)f2h(v.y) << 16)
                        | ((unsigned long long)f2h(v.z) << 32)
                        | ((unsigned long long)f2h(v.w) << 48);
  *(unsigned long long*)(dst + off4 * 4) = pk;
}

// ---------------------------------------------------------------- QKV GEMM
// (unchanged — verified; K/V frag layouts identical)
__device__ __forceinline__ void gemm_stage(
    const unsigned short* __restrict__ xb, const unsigned short* __restrict__ wcat,
    char* smem, int buf, int mbase, int nbase, int kt, int wv, int lane, int srcg) {
  char* base = smem + buf * 32768;
  const int kbase = kt * 64;
  if (wv < 2) {
    #pragma unroll
    for (int i = 0; i < 8; ++i) {
      const int blk = wv * 8 + i;
      const int row = blk * 8 + (lane >> 3);
      gload_lds16(xb + (size_t)(mbase + row) * 512 + kbase + srcg, base + blk * 1024);
    }
  } else {
    #pragma unroll
    for (int i = 0; i < 8; ++i) {
      const int blk = (wv - 2) * 8 + i;
      const int row = blk * 8 + (lane >> 3);
      gload_lds16(wcat + (size_t)(nbase + row) * 512 + kbase + srcg, base + 16384 + blk * 1024);
    }
  }
}

__global__ __launch_bounds__(256, 2) void gemm_qkv(
    const unsigned short* __restrict__ xb, const unsigned short* __restrict__ wcat,
    unsigned short* __restrict__ Qb, unsigned short* __restrict__ Kf,
    unsigned short* __restrict__ Vtb) {
  __shared__ char smem[65536];
  const int tid = threadIdx.x, lane = tid & 63, wv = tid >> 6;
  const int wr = wv >> 1, wc = wv & 1;
  const int l15 = lane & 15, l4 = lane >> 4;
  const int mbase = blockIdx.x * 128;
  const int nbase = blockIdx.y * 128;
  const int srcg = (((lane & 7) ^ ((lane >> 3) & 7))) * 8;

  f32x4 acc[4][4];
  #pragma unroll
  for (int i = 0; i < 4; ++i)
    #pragma unroll
    for (int j = 0; j < 4; ++j) acc[i][j] = (f32x4){0.f, 0.f, 0.f, 0.f};

  gemm_stage(xb, wcat, smem, 0, mbase, nbase, 0, wv, lane, srcg);
  for (int kt = 0; kt < 8; ++kt) {
    __syncthreads();
    if (kt < 7) gemm_stage(xb, wcat, smem, (kt + 1) & 1, mbase, nbase, kt + 1, wv, lane, srcg);
    const char* base = smem + (kt & 1) * 32768;
    #pragma unroll
    for (int ks = 0; ks < 2; ++ks) {
      half8 a[4], b8[4];
      #pragma unroll
      for (int rt = 0; rt < 4; ++rt) {
        const int row = wr * 64 + rt * 16 + l15;
        const int G = (ks * 4 + l4) ^ (row & 7);
        a[rt] = *(const half8*)(base + row * 128 + G * 16);
      }
      #pragma unroll
      for (int ct = 0; ct < 4; ++ct) {
        const int row = wc * 64 + ct * 16 + l15;
        const int G = (ks * 4 + l4) ^ (row & 7);
        b8[ct] = *(const half8*)(base + 16384 + row * 128 + G * 16);
      }
      #pragma unroll
      for (int rt = 0; rt < 4; ++rt)
        #pragma unroll
        for (int ct = 0; ct < 4; ++ct)
          acc[rt][ct] = __builtin_amdgcn_mfma_f32_16x16x32_f16(a[rt], b8[ct], acc[rt][ct], 0, 0, 0);
    }
  }

  const int mat = nbase >> 9;          // 0=Q, 1=K, 2=V
  const int nloc = nbase & 511;
  if (mat == 0) {
    #pragma unroll
    for (int rt = 0; rt < 4; ++rt)
      #pragma unroll
      for (int ct = 0; ct < 4; ++ct) {
        const int m0 = mbase + wr * 64 + rt * 16 + l4 * 4;
        const int n = nloc + wc * 64 + ct * 16 + l15;
        #pragma unroll
        for (int j = 0; j < 4; ++j)
          Qb[(size_t)(m0 + j) * 512 + n] = f2h(acc[rt][ct][j]);
      }
  } else if (mat == 1) {
    // K in flash A-frag order
    #pragma unroll
    for (int rt = 0; rt < 4; ++rt)
      #pragma unroll
      for (int ct = 0; ct < 4; ++ct) {
        const int m0 = mbase + wr * 64 + rt * 16 + l4 * 4;
        const int d = nloc + wc * 64 + ct * 16 + l15;
        const int s = d >> 4, hh = (d >> 3) & 1, e = d & 7;
        #pragma unroll
        for (int j = 0; j < 4; ++j) {
          const int t = m0 + j;
          const int bb = t >> 11, tt = t & 2047;
          const size_t blk =
              ((((size_t)bb * 64 + (tt >> 5)) * 32 + s) * 32 + (tt & 31)) * 2 + hh;
          Kf[blk * 8 + e] = f2h(acc[rt][ct][j]);
        }
      }
  } else {
    // V in flash frag order; j..j+3 stay within one 16B block
    #pragma unroll
    for (int rt = 0; rt < 4; ++rt)
      #pragma unroll
      for (int ct = 0; ct < 4; ++ct) {
        const int m0 = mbase + wr * 64 + rt * 16 + l4 * 4;
        const int d = nloc + wc * 64 + ct * 16 + l15;
        const int bb = m0 >> 11, t = m0 & 2047;
        const int kvt = t >> 7, u = (t >> 3) & 15, jj = t & 7;
        unsigned long long pk = (unsigned long long)f2h(acc[rt][ct][0])
                              | ((unsigned long long)f2h(acc[rt][ct][1]) << 16)
                              | ((unsigned long long)f2h(acc[rt][ct][2]) << 32)
                              | ((unsigned long long)f2h(acc[rt][ct][3]) << 48);
        *(unsigned long long*)(Vtb + ((((size_t)bb * 16 + kvt) * 16 + u) * 512 + d) * 8 + jj) = pk;
      }
  }
}

// ---------------------------------------------------------------- flash attention
// 256 WGs x 16 waves; b = blk&7 (XCD), qt = 31-(blk>>3) (64 q-rows, long first).
// nkv = (qt+8)>>3 steps of KVBLK=512 (max 4). Fully unconditional control flow.
// QK: wave ks=wv (strip 32 kv): TWO chains = both q-halves off one kf read;
//     causal mask+scale IN PLACE into the accumulators (no v[] arrays).
// PV: wave owns d strip [wv*32..+32): O^T[q2] += mfma32(V_frag, P_lds).
__global__ __launch_bounds__(1024, 4) void flash_kernel(
    const unsigned short* __restrict__ Qb, const unsigned short* __restrict__ Kf,
    const unsigned short* __restrict__ Vtb, float* __restrict__ out) {
  extern __shared__ char smem[];

  const int tid = threadIdx.x, lane = tid & 63, wv = tid >> 6;   // 16 waves
  const int l31 = lane & 31, h = lane >> 5;
  const int ks = wv;                               // kv strip 0..15 in 512-block
  const int b = blockIdx.x & 7;                    // batch == XCD
  const int qt = 31 - (blockIdx.x >> 3);           // 64-row tile, long first
  const size_t bT = (size_t)b * T_;
  const int nkv = (qt + 8) >> 3;

  // ---- stage Q [64][512] once: LDS[r] granule g = Q[r][g ^ (r&31)] ----
  {
    const unsigned short* src = Qb + (bT + (size_t)qt * 64) * 512;
    #pragma unroll
    for (int i = 0; i < 4; ++i) {
      const int r = wv * 4 + i;
      gload_lds16(src + (size_t)r * 512 + ((lane ^ (r & 31)) * 8), smem + r * 1024);
    }
  }
  asm volatile("s_waitcnt vmcnt(0)" ::: "memory");
  __builtin_amdgcn_s_barrier();

  f32x16 o[2];                                     // o[q2]: O^T [32 d][32 q]
  #pragma unroll
  for (int q2 = 0; q2 < 2; ++q2)
    #pragma unroll
    for (int r = 0; r < 16; ++r) o[q2][r] = 0.f;
  float lreg[2] = {0.f, 0.f};
  float mqpv[2] = {-1e30f, -1e30f};
  float mqk[2] = {-1e30f, -1e30f};

  for (int kv = 0; kv < nkv; ++kv) {
    const int kv0 = kv * 512;
    const int p = kv & 1;
    char* Pp = smem + FL_P;
    float* stxp = (float*)(smem + FL_STX + p * 5120);
    float* stsp = (float*)(smem + FL_STS + p * 5120);

    // ---- QK^T swapped, both q-halves off one kf read (unconditional) ----
    f32x16 acc0, acc1;
    #pragma unroll
    for (int r = 0; r < 16; ++r) { acc0[r] = 0.f; acc1[r] = 0.f; }
    {
      const unsigned short* kp =
          Kf + (((size_t)b * 64 + (kv * 16 + ks)) << 14) + l31 * 16 + h * 8;
      const char* qb0 = smem + l31 * 1024;
      const char* qb1 = smem + (32 + l31) * 1024;
      #pragma unroll
      for (int sg = 0; sg < 8; ++sg) {             // groups of 4: kf transient
        half8 kf4[4];
        #pragma unroll
        for (int i = 0; i < 4; ++i)
          kf4[i] = *(const half8*)(kp + (sg * 4 + i) * 512);
        #pragma unroll
        for (int i = 0; i < 4; ++i) {
          const int go = (((sg * 4 + i) * 2 + h) ^ l31) << 4;
          acc0 = __builtin_amdgcn_mfma_f32_32x32x16_f16(kf4[i], *(const half8*)(qb0 + go), acc0, 0, 0, 0);
          acc1 = __builtin_amdgcn_mfma_f32_32x32x16_f16(kf4[i], *(const half8*)(qb1 + go), acc1, 0, 0, 0);
        }
      }
    }

    // ---- scale + causal mask IN PLACE + in-lane strip max ----
    float tm0 = -1e30f, tm1 = -1e30f;
    {
      const int qg0 = qt * 64 + l31;
      const int qg1 = qg0 + 32;
      #pragma unroll
      for (int r = 0; r < 16; ++r) {
        const int kvg = kv0 + ks * 32 + (r & 3) + 8 * (r >> 2) + 4 * h;
        acc0[r] = (kvg <= qg0) ? acc0[r] * SCALE_ : -1e30f;
        acc1[r] = (kvg <= qg1) ? acc1[r] * SCALE_ : -1e30f;
        tm0 = fmaxf(tm0, acc0[r]);
        tm1 = fmaxf(tm1, acc1[r]);
      }
    }
    tm0 = fmaxf(tm0, __shfl_xor(tm0, 32, 64));
    tm1 = fmaxf(tm1, __shfl_xor(tm1, 32, 64));
    if (h == 0) { stxp[l31 * 20 + ks] = tm0; stxp[(32 + l31) * 20 + ks] = tm1; }
    barrier_lgkm();                                // B: strip maxes visible

    // ---- softmax (halves sequential; per-lane scalar state; acc read direct) ----
    #pragma unroll
    for (int hf = 0; hf < 2; ++hf) {
      const int r0 = hf * 32 + l31;
      const float* sx = stxp + r0 * 20;
      float mn = mqk[hf];
      #pragma unroll
      for (int i = 0; i < 4; ++i) {
        const f32x4 x = *(const f32x4*)(sx + i * 4);
        mn = fmaxf(mn, fmaxf(fmaxf(x[0], x[1]), fmaxf(x[2], x[3])));
      }
      mqk[hf] = mn;
      const f32x16& vv = hf ? acc1 : acc0;
      float ps = 0.f;
      #pragma unroll
      for (int c = 0; c < 4; ++c) {                // P -> LDS, b64 packed
        unsigned long long pk = 0;
        #pragma unroll
        for (int j = 0; j < 4; ++j) {
          const unsigned short hj = f2h(__expf(vv[4 * c + j] - mn));
          ps += (float)*(const _Float16*)&hj;      // sum the rounded values
          pk |= (unsigned long long)hj << (16 * j);
        }
        *(unsigned long long*)(Pp + r0 * 1024 +
                               ((((ks * 4 + c) ^ (r0 & 31))) << 4) + h * 8) = pk;
      }
      ps += __shfl_xor(ps, 32, 64);
      if (h == 0) stsp[r0 * 20 + ks] = ps;
    }
    barrier_lgkm();                                // C: P + stats visible

    // ---- per-lane alpha/l update, rescale O ----
    #pragma unroll
    for (int q2 = 0; q2 < 2; ++q2) {
      const int r0 = q2 * 32 + l31;
      const float* sx = stxp + r0 * 20;
      float mn2 = mqpv[q2];
      #pragma unroll
      for (int i = 0; i < 4; ++i) {
        const f32x4 x = *(const f32x4*)(sx + i * 4);
        mn2 = fmaxf(mn2, fmaxf(fmaxf(x[0], x[1]), fmaxf(x[2], x[3])));
      }
      const float a = __expf(mqpv[q2] - mn2);
      mqpv[q2] = mn2;
      const float* ss = stsp + r0 * 20;
      float sum = 0.f;
      #pragma unroll
      for (int i = 0; i < 4; ++i) {
        const f32x4 x = *(const f32x4*)(ss + i * 4);
        sum += (x[0] + x[1]) + (x[2] + x[3]);
      }
      lreg[q2] = a * lreg[q2] + sum;
      #pragma unroll
      for (int r = 0; r < 16; ++r) o[q2][r] *= a;
    }

    // ---- PV: O^T += Vt x P over 512 kv; 8 groups of 4 chunks (vf transient),
    // ---- unconditional (masked chunks have P=0) ----
    const int d = wv * 32 + l31;
    #pragma unroll
    for (int g = 0; g < 8; ++g) {
      half8 vf[4];
      #pragma unroll
      for (int s4 = 0; s4 < 4; ++s4) {
        const int S = g * 4 + s4;
        const size_t vblk = ((size_t)b * 16 + (kv * 4 + (S >> 3))) * 16;
        vf[s4] = *(const half8*)(Vtb + ((vblk + (S & 7) * 2 + h) * 512 + d) * 8);
      }
      #pragma unroll
      for (int s4 = 0; s4 < 4; ++s4) {
        const int S = g * 4 + s4;
        #pragma unroll
        for (int q2 = 0; q2 < 2; ++q2) {
          const half8 pa = *(const half8*)(Pp + (q2 * 32 + l31) * 1024 +
                                           (((S * 2 + h) ^ l31) << 4));
          o[q2] = __builtin_amdgcn_mfma_f32_32x32x16_f16(vf[s4], pa, o[q2], 0, 0, 0);
        }
      }
    }
  }

  barrier_lgkm();                                  // all PV P-reads done (scratch reuse)

  // ---- epilogue: transpose O^T via per-wave scratch, /l, coalesced stores ----
  {
    char* scr = smem + wv * 4608;                  // 32 rows x 144B
    const float linv[2] = {1.0f / lreg[0], 1.0f / lreg[1]};
    #pragma unroll
    for (int q2 = 0; q2 < 2; ++q2) {
      #pragma unroll
      for (int c = 0; c < 4; ++c) {
        f32x4 w4;
        #pragma unroll
        for (int j = 0; j < 4; ++j) w4[j] = o[q2][4 * c + j] * linv[q2];
        *(f32x4*)(scr + l31 * 144 + c * 32 + h * 16) = w4;   // scr[q][d]
      }
      asm volatile("s_waitcnt lgkmcnt(0)" ::: "memory");
      #pragma unroll
      for (int g = 0; g < 4; ++g) {
        const int qr = g * 8 + (lane >> 3);
        const f32x4 r4 = *(const f32x4*)(scr + qr * 144 + (lane & 7) * 16);
        *(f32x4*)(out + (bT + qt * 64 + q2 * 32 + qr) * 512 +
                  wv * 32 + (lane & 7) * 4) = r4;
      }
      asm volatile("s_waitcnt lgkmcnt(0)" ::: "memory");
    }
  }
}

// ---------------------------------------------------------------- launch
extern "C" void kernel_launch(void* const* d_in, const int* in_sizes, int n_in,
                              void* d_out, int out_size, void* d_ws, size_t ws_size,
                              hipStream_t stream) {
  (void)in_sizes; (void)n_in; (void)out_size; (void)ws_size;
  const float* x  = (const float*)d_in[0];
  const float* wq = (const float*)d_in[1];
  const float* wk = (const float*)d_in[2];
  const float* wv = (const float*)d_in[3];
  float* out = (float*)d_out;

  unsigned short* ws   = (unsigned short*)d_ws;
  unsigned short* xb   = ws;                                    // [16384][512]
  unsigned short* wcat = xb + (size_t)16384 * 512;              // [1536][512]
  unsigned short* Qb   = wcat + (size_t)1536 * 512;             // [16384][512] row-major
  unsigned short* Kf   = Qb + (size_t)16384 * 512;              // [8][64][32][32][2][8] frag order
  unsigned short* Vtb  = Kf + (size_t)16384 * 512;              // [8][16][16][512][8] frag order
  // total ws use: 68.7 MB

  cast_kernel<<<8960, 256, 0, stream>>>(x, wq, wk, wv, xb, wcat);
  gemm_qkv<<<dim3(128, 12), 256, 0, stream>>>(xb, wcat, Qb, Kf, Vtb);
  hipFuncSetAttribute(reinterpret_cast<const void*>(flash_kernel),
                      hipFuncAttributeMaxDynamicSharedMemorySize, FL_SMEM);
  flash_kernel<<<256, 1024, FL_SMEM, stream>>>(Qb, Kf, Vtb, out);
}